// Round 9
// baseline (86.458 us; speedup 1.0000x reference)
//
#include <hip/hip_runtime.h>
#include <hip/hip_bf16.h>

#define B_ROWS 4096
#define D_DIM  512
#define N_ROWS 8192
#define INV_T  20.0f
#define L2E_T  28.853900817779268f             // 20 / ln(2): exp(20x) = exp2(x*L2E_T)
#define EPS_N  1e-8f
#define CSPLIT 8
#define BM 256                                  // rows per block
#define BN 256                                  // cols per strip
#define COLS_PER_CHUNK (N_ROWS / CSPLIT)        // 1024
#define STRIPS (COLS_PER_CHUNK / BN)            // 4
#define NIT (STRIPS * 8)                        // 32 (8 K-steps of 64 fp8)
#define TILE_BYTES 16384                        // one K-step tile: [8 kslot][256 row][8B]
#define BUF_BYTES  (2 * TILE_BYTES)             // A + B
#define PANEL_BYTES 131072                      // [64 kslot][256 row][8B] per 256-row panel

typedef __attribute__((ext_vector_type(16))) float floatx16;

#define AS1C(p) ((const __attribute__((address_space(1))) void*)(p))
#define AS3(p)  ((__attribute__((address_space(3))) void*)(p))

// k-major LDS tile: [8 kslots][256 rows][8B]; lanes reading consecutive rows at
// one kslot touch 256 CONTIGUOUS bytes -> conflict-free by construction
__device__ __forceinline__ long ldsFrag8(const char* base, int row, int kslot) {
  return *(const long*)(base + kslot * 2048 + row * 8);
}

// sorted-insert via med3: new_t[i] = median(v, t[i], t[i-1]); all-ILP
__device__ __forceinline__ void insert5(float (&t)[5], float v) {
  float n0 = fmaxf(t[0], v);
  float n1 = __builtin_amdgcn_fmed3f(v, t[1], t[0]);
  float n2 = __builtin_amdgcn_fmed3f(v, t[2], t[1]);
  float n3 = __builtin_amdgcn_fmed3f(v, t[3], t[2]);
  float n4 = __builtin_amdgcn_fmed3f(v, t[4], t[3]);
  t[0] = n0; t[1] = n1; t[2] = n2; t[3] = n3; t[4] = n4;
}

// scan one strip: exp-sum + top-5 (diag already poisoned to -inf)
__device__ __forceinline__ void scan_acc(floatx16 (&acc)[2][2], float (&sum)[2],
                                         float (&top)[2][5]) {
  #pragma unroll
  for (int rb = 0; rb < 2; ++rb)
    #pragma unroll
    for (int cb = 0; cb < 2; ++cb)
      #pragma unroll
      for (int r = 0; r < 16; ++r) {
        float ev = exp2f(acc[rb][cb][r] * L2E_T);
        sum[rb] += ev;
        insert5(top[rb], ev);
      }
}

// stage one K-step A tile + B tile (each a contiguous 16 KB identity copy).
// waves 0-7 stage A (2 KB each = one kslot), waves 8-15 stage B.
__device__ __forceinline__ void stage_tile(const char* gA_t, const char* gB_t,
                                           char* buf, int wave, int lane) {
  const char* src = (wave < 8) ? gA_t : gB_t;
  char* dstbase = buf + ((wave < 8) ? 0 : TILE_BYTES) + (wave & 7) * 2048;
  int so = (wave & 7) * 2048 + lane * 16;
  #pragma unroll
  for (int q = 0; q < 2; ++q)
    __builtin_amdgcn_global_load_lds(AS1C(src + so + q * 1024),
                                     AS3(dstbase + q * 1024), 16, 0, 0);
}

// ---- kernel 1: normalize -> fp8 e4m3 in panel-K-major layout, dot(f1,f2) ----
__global__ __launch_bounds__(256) void prep_kernel(
    const float* __restrict__ f1, const float* __restrict__ f2,
    unsigned char* __restrict__ fnb8, float* __restrict__ dots)
{
  int row = blockIdx.x;          // 0..4095
  int t = threadIdx.x;           // 256 threads, 2 elems each for the reduction
  const float* r1 = f1 + (size_t)row * D_DIM;
  const float* r2 = f2 + (size_t)row * D_DIM;
  float2 a = *(const float2*)(r1 + 2 * t);
  float2 b = *(const float2*)(r2 + 2 * t);
  float s1 = a.x * a.x + a.y * a.y;
  float s2 = b.x * b.x + b.y * b.y;
  float d  = a.x * b.x + a.y * b.y;
  #pragma unroll
  for (int off = 32; off >= 1; off >>= 1) {
    s1 += __shfl_down(s1, off);
    s2 += __shfl_down(s2, off);
    d  += __shfl_down(d, off);
  }
  __shared__ float red[4][3];
  __shared__ float bc[2];
  int wave = t >> 6, lane = t & 63;
  if (lane == 0) { red[wave][0] = s1; red[wave][1] = s2; red[wave][2] = d; }
  __syncthreads();
  if (t == 0) {
    float S1 = red[0][0] + red[1][0] + red[2][0] + red[3][0];
    float S2 = red[0][1] + red[1][1] + red[2][1] + red[3][1];
    float Dd = red[0][2] + red[1][2] + red[2][2] + red[3][2];
    bc[0] = 1.0f / fmaxf(sqrtf(S1), EPS_N);
    bc[1] = 1.0f / fmaxf(sqrtf(S2), EPS_N);
    dots[row] = Dd;
  }
  __syncthreads();
  // phase 2: threads 0-63 pack f1 (kslot = t), 64-127 pack f2
  if (t < 128) {
    int g = t & 63;                        // kslot
    int is2 = t >> 6;
    const float* src = (is2 ? f2 : f1) + (size_t)row * D_DIM + g * 8;
    float sc = bc[is2];
    float4 v0 = *(const float4*)(src);
    float4 v1 = *(const float4*)(src + 4);
    int lo = __builtin_amdgcn_cvt_pk_fp8_f32(v0.x * sc, v0.y * sc, 0, false);
    lo     = __builtin_amdgcn_cvt_pk_fp8_f32(v0.z * sc, v0.w * sc, lo, true);
    int hi = __builtin_amdgcn_cvt_pk_fp8_f32(v1.x * sc, v1.y * sc, 0, false);
    hi     = __builtin_amdgcn_cvt_pk_fp8_f32(v1.z * sc, v1.w * sc, hi, true);
    int grow = row + is2 * B_ROWS;
    int panel = grow >> 8, rin = grow & 255;
    int2 pack; pack.x = lo; pack.y = hi;
    *(int2*)(fnb8 + (size_t)panel * PANEL_BYTES + g * 2048 + rin * 8) = pack;
  }
}

// ---- kernel 2: fp8 32x32 swapped-operand MFMA sim + in-register exp-sum/top-5 ----
// 1024 thr, 4x4 wave grid, wave tile 64x64; 4 waves/EU (64 AGPR acc + ~64 VGPR)
__global__ __launch_bounds__(1024, 4) void sim_kernel(
    const unsigned char* __restrict__ fnb8,
    float* __restrict__ partials)      // [N_ROWS][CSPLIT][6] = sum, top5 (desc)
{
  __shared__ int4 lds4[4096];          // 64 KiB = 2 double-buffers of (A+B)
  char* lds = (char*)lds4;

  // XCD-bijective mapping: XCD (bx&7) owns rowtiles 4x..4x+3 across all chunks
  int bx = blockIdx.x;                 // 0..255
  int xcd = bx & 7, kk = bx >> 3;      // kk: 0..31
  int rt = xcd * 4 + (kk & 3);         // 0..31  (= A panel index)
  int chunk = kk >> 2;                 // 0..7
  int rowbase = rt * BM;
  int chunkbase = chunk * COLS_PER_CHUNK;

  int t = threadIdx.x;
  int wave = t >> 6, lane = t & 63;
  int wr = wave >> 2, wc = wave & 3;   // 4x4 wave grid; wave tile 64x64
  int l31 = lane & 31, lh = lane >> 5;

  float sum[2];
  float top[2][5];
  floatx16 acc[2][2];
  #pragma unroll
  for (int rb = 0; rb < 2; ++rb) {
    sum[rb] = 0.f;
    #pragma unroll
    for (int k = 0; k < 5; ++k) top[rb][k] = 0.f;
    #pragma unroll
    for (int cb = 0; cb < 2; ++cb)
      #pragma unroll
      for (int e = 0; e < 16; ++e) acc[rb][cb][e] = 0.0f;
  }

  const char* gA  = (const char*)fnb8 + (size_t)rt * PANEL_BYTES;
  const char* gB0 = (const char*)fnb8 + (size_t)(chunk * 4) * PANEL_BYTES;

  stage_tile(gA, gB0, lds, wave, lane);
  __syncthreads();                     // drains vmcnt -> tile 0 resident

  for (int it = 0; it < NIT; ++it) {
    int strip = it >> 3, kstep = it & 7, cur = it & 1;

    if (it + 1 < NIT) {
      int ns = (it + 1) >> 3, nk = (it + 1) & 7;
      stage_tile(gA + nk * TILE_BYTES,
                 gB0 + (size_t)ns * PANEL_BYTES + nk * TILE_BYTES,
                 lds + (cur ^ 1) * BUF_BYTES, wave, lane);
    }

    const char* As = lds + cur * BUF_BYTES;
    const char* Bs = As + TILE_BYTES;
    #pragma unroll
    for (int ks = 0; ks < 4; ++ks) {
      int kslot = ks * 2 + lh;
      long rf0 = ldsFrag8(As, wr * 64 + l31,      kslot);
      long rf1 = ldsFrag8(As, wr * 64 + 32 + l31, kslot);
      long cf0 = ldsFrag8(Bs, wc * 64 + l31,      kslot);
      long cf1 = ldsFrag8(Bs, wc * 64 + 32 + l31, kslot);
      acc[0][0] = __builtin_amdgcn_mfma_f32_32x32x16_fp8_fp8(cf0, rf0, acc[0][0], 0, 0, 0);
      acc[0][1] = __builtin_amdgcn_mfma_f32_32x32x16_fp8_fp8(cf1, rf0, acc[0][1], 0, 0, 0);
      acc[1][0] = __builtin_amdgcn_mfma_f32_32x32x16_fp8_fp8(cf0, rf1, acc[1][0], 0, 0, 0);
      acc[1][1] = __builtin_amdgcn_mfma_f32_32x32x16_fp8_fp8(cf1, rf1, acc[1][1], 0, 0, 0);
    }

    if (kstep == 7) {                  // strip complete: poison diag, scan, reset
      // diagonal sub-block: this wave's rows == this strip's cols (wave-uniform)
      bool dwave = (rowbase + wr * 64) == (chunkbase + strip * BN + wc * 64);
      if (dwave && (((l31 >> 2) & 1) == lh)) {
        int rd = (l31 & 3) | (((l31 >> 3) & 3) << 2);
        acc[0][0][rd] = -1e30f;        // exp2 -> 0 (exact diag exclusion)
        acc[1][1][rd] = -1e30f;
      }
      scan_acc(acc, sum, top);
      #pragma unroll
      for (int rb = 0; rb < 2; ++rb)
        #pragma unroll
        for (int cb = 0; cb < 2; ++cb)
          #pragma unroll
          for (int e = 0; e < 16; ++e) acc[rb][cb][e] = 0.0f;
    }

    __syncthreads();                   // reads of cur done + next tile resident
  }

  // merge lane l <-> l+32 (same sim-rows, disjoint col subsets)
  #pragma unroll
  for (int rb = 0; rb < 2; ++rb) {
    sum[rb] += __shfl_xor(sum[rb], 32);
    float pt[5];
    #pragma unroll
    for (int k = 0; k < 5; ++k) pt[k] = __shfl_xor(top[rb][k], 32);
    #pragma unroll
    for (int k = 0; k < 5; ++k) insert5(top[rb], pt[k]);
  }

  // cross-wave merge: 4 wc-waves hold disjoint col ranges of the same rows
  float* mbuf = (float*)lds;           // [16 waves][2 rb][32 lanes][6] = 24 KiB
  if (lane < 32) {
    #pragma unroll
    for (int rb = 0; rb < 2; ++rb) {
      float* dst = mbuf + (size_t)(((wave * 2 + rb) * 32) + lane) * 6;
      dst[0] = sum[rb];
      #pragma unroll
      for (int k = 0; k < 5; ++k) dst[1 + k] = top[rb][k];
    }
  }
  __syncthreads();
  if (t < 256) {                       // thread t owns block-row t
    int wr2 = t >> 6, rb2 = (t >> 5) & 1, r31 = t & 31;
    float s = 0.0f;
    float a5[5] = {0.f, 0.f, 0.f, 0.f, 0.f};
    #pragma unroll
    for (int wc2 = 0; wc2 < 4; ++wc2) {
      int w = wr2 * 4 + wc2;
      const float* src = mbuf + (size_t)(((w * 2 + rb2) * 32) + r31) * 6;
      s += src[0];
      #pragma unroll
      for (int k = 0; k < 5; ++k) insert5(a5, src[1 + k]);
    }
    int grow = rowbase + t;
    float* dst = partials + ((size_t)grow * CSPLIT + chunk) * 6;
    dst[0] = s;
    #pragma unroll
    for (int k = 0; k < 5; ++k) dst[1 + k] = a5[k];
  }
}

// -------------------- kernel 3a: per-row loss, 32-block partial sums ----------
__global__ __launch_bounds__(256) void finalize1_kernel(
    const float* __restrict__ partials, const float* __restrict__ dots,
    float* __restrict__ bpart)
{
  int row = blockIdx.x * 256 + threadIdx.x;    // 32*256 = 8192
  const float* p = partials + (size_t)row * (CSPLIT * 6);
  float s = 0.0f;
  float a5[5] = {0.f, 0.f, 0.f, 0.f, 0.f};
  #pragma unroll
  for (int c = 0; c < CSPLIT; ++c) {
    s += p[c * 6];
    #pragma unroll
    for (int k = 0; k < 5; ++k) insert5(a5, p[c * 6 + 1 + k]);
  }
  float ng = s - (a5[0] + a5[1] + a5[2] + a5[3] + a5[4]);
  float dv = dots[row & (B_ROWS - 1)];
  float acc = __logf(ng + __expf(dv * INV_T)) - dv * INV_T;

  #pragma unroll
  for (int off = 32; off >= 1; off >>= 1) acc += __shfl_down(acc, off);
  __shared__ float red[4];
  int wave = threadIdx.x >> 6, lane = threadIdx.x & 63;
  if (lane == 0) red[wave] = acc;
  __syncthreads();
  if (threadIdx.x == 0)
    bpart[blockIdx.x] = red[0] + red[1] + red[2] + red[3];
}

// -------------------- kernel 3b: final reduce --------------------
__global__ __launch_bounds__(64) void finalize2_kernel(
    const float* __restrict__ bpart, float* __restrict__ out)
{
  int t = threadIdx.x;
  float v = (t < 32) ? bpart[t] : 0.0f;
  #pragma unroll
  for (int off = 32; off >= 1; off >>= 1) v += __shfl_down(v, off);
  if (t == 0) out[0] = v / (float)N_ROWS;
}

extern "C" void kernel_launch(void* const* d_in, const int* in_sizes, int n_in,
                              void* d_out, int out_size, void* d_ws, size_t ws_size,
                              hipStream_t stream) {
  const float* f1 = (const float*)d_in[0];
  const float* f2 = (const float*)d_in[1];
  float* out = (float*)d_out;
  char* ws = (char*)d_ws;

  unsigned char* fnb8 = (unsigned char*)ws;                           // 4 MiB
  float* dots = (float*)(ws + (size_t)4 * 1024 * 1024);               // 16 KiB
  float* partials = (float*)(ws + (size_t)4 * 1024 * 1024 + 65536);   // 1.5 MiB
  float* bpart = (float*)(ws + (size_t)8 * 1024 * 1024);              // 128 B

  prep_kernel<<<B_ROWS, 256, 0, stream>>>(f1, f2, fnb8, dots);
  sim_kernel<<<(N_ROWS / BM) * CSPLIT, 1024, 0, stream>>>(fnb8, partials);
  finalize1_kernel<<<32, 256, 0, stream>>>(partials, dots, bpart);
  finalize2_kernel<<<1, 64, 0, stream>>>(bpart, out);
}

// Round 10
// 86.310 us; speedup vs baseline: 1.0017x; 1.0017x over previous
//
#include <hip/hip_runtime.h>
#include <hip/hip_bf16.h>

#define B_ROWS 4096
#define D_DIM  512
#define N_ROWS 8192
#define INV_T  20.0f
#define L2E_T  28.853900817779268f             // 20 / ln(2): exp(20x) = exp2(x*L2E_T)
#define EPS_N  1e-8f
#define CSPLIT 8
#define BM 128                                  // rows per block
#define BN 256                                  // cols per strip
#define COLS_PER_CHUNK (N_ROWS / CSPLIT)        // 1024
#define STRIPS (COLS_PER_CHUNK / BN)            // 4
#define NIT (STRIPS * 8)                        // 32 (8 K-steps of 64 fp8)
#define TILE_A 8192                             // [8 kslot][128 row][8B]
#define TILE_B 16384                            // [8 kslot][256 row][8B]
#define BUF_BYTES (TILE_A + TILE_B)             // 24 KiB
#define PANEL_BYTES 131072                      // [64 kslot][256 row][8B] per 256-row panel
#define KSTEP_BYTES 16384                       // 8 kslots x 256 rows x 8B in a panel

typedef __attribute__((ext_vector_type(16))) float floatx16;

#define AS1C(p) ((const __attribute__((address_space(1))) void*)(p))
#define AS3(p)  ((__attribute__((address_space(3))) void*)(p))

// k-major LDS tiles; lanes reading consecutive rows at one kslot touch
// contiguous bytes -> conflict-free by construction (verified R9: 0 conflicts)
__device__ __forceinline__ long ldsFragA(const char* base, int row, int kslot) {
  return *(const long*)(base + kslot * 1024 + row * 8);   // 128-row tile
}
__device__ __forceinline__ long ldsFragB(const char* base, int row, int kslot) {
  return *(const long*)(base + kslot * 2048 + row * 8);   // 256-row tile
}

// sorted-insert via med3: new_t[i] = median(v, t[i], t[i-1]); all-ILP
__device__ __forceinline__ void insert5(float (&t)[5], float v) {
  float n0 = fmaxf(t[0], v);
  float n1 = __builtin_amdgcn_fmed3f(v, t[1], t[0]);
  float n2 = __builtin_amdgcn_fmed3f(v, t[2], t[1]);
  float n3 = __builtin_amdgcn_fmed3f(v, t[3], t[2]);
  float n4 = __builtin_amdgcn_fmed3f(v, t[4], t[3]);
  t[0] = n0; t[1] = n1; t[2] = n2; t[3] = n3; t[4] = n4;
}

// scan one strip: exp-sum + top-5 (diag already poisoned to -inf)
__device__ __forceinline__ void scan_acc(floatx16 (&acc)[2][2], float (&sum)[2],
                                         float (&top)[2][5]) {
  #pragma unroll
  for (int rb = 0; rb < 2; ++rb)
    #pragma unroll
    for (int cb = 0; cb < 2; ++cb)
      #pragma unroll
      for (int r = 0; r < 16; ++r) {
        float ev = exp2f(acc[rb][cb][r] * L2E_T);
        sum[rb] += ev;
        insert5(top[rb], ev);
      }
}

// stage one K-step: A tile (8 KB, 128 rows) + B tile (16 KB, 256 rows).
// 8 waves: wave w stages kslot w of A (1 instr) and kslot w of B (2 instr).
// gA_t points at panelA + kstep*KSTEP_BYTES + rhalf*1024 (A kslot stride 2048);
// gB_t points at panelB + kstep*KSTEP_BYTES (full 256 rows, contiguous 2KB).
__device__ __forceinline__ void stage_tile(const char* gA_t, const char* gB_t,
                                           char* buf, int wave, int lane) {
  int w = wave & 7;
  __builtin_amdgcn_global_load_lds(AS1C(gA_t + w * 2048 + lane * 16),
                                   AS3(buf + w * 1024), 16, 0, 0);
  #pragma unroll
  for (int q = 0; q < 2; ++q)
    __builtin_amdgcn_global_load_lds(AS1C(gB_t + w * 2048 + q * 1024 + lane * 16),
                                     AS3(buf + TILE_A + w * 2048 + q * 1024), 16, 0, 0);
}

// ---- kernel 1: normalize -> fp8 e4m3 in panel-K-major layout, dot(f1,f2) ----
__global__ __launch_bounds__(256) void prep_kernel(
    const float* __restrict__ f1, const float* __restrict__ f2,
    unsigned char* __restrict__ fnb8, float* __restrict__ dots)
{
  int row = blockIdx.x;          // 0..4095
  int t = threadIdx.x;           // 256 threads, 2 elems each for the reduction
  const float* r1 = f1 + (size_t)row * D_DIM;
  const float* r2 = f2 + (size_t)row * D_DIM;
  float2 a = *(const float2*)(r1 + 2 * t);
  float2 b = *(const float2*)(r2 + 2 * t);
  float s1 = a.x * a.x + a.y * a.y;
  float s2 = b.x * b.x + b.y * b.y;
  float d  = a.x * b.x + a.y * b.y;
  #pragma unroll
  for (int off = 32; off >= 1; off >>= 1) {
    s1 += __shfl_down(s1, off);
    s2 += __shfl_down(s2, off);
    d  += __shfl_down(d, off);
  }
  __shared__ float red[4][3];
  __shared__ float bc[2];
  int wave = t >> 6, lane = t & 63;
  if (lane == 0) { red[wave][0] = s1; red[wave][1] = s2; red[wave][2] = d; }
  __syncthreads();
  if (t == 0) {
    float S1 = red[0][0] + red[1][0] + red[2][0] + red[3][0];
    float S2 = red[0][1] + red[1][1] + red[2][1] + red[3][1];
    float Dd = red[0][2] + red[1][2] + red[2][2] + red[3][2];
    bc[0] = 1.0f / fmaxf(sqrtf(S1), EPS_N);
    bc[1] = 1.0f / fmaxf(sqrtf(S2), EPS_N);
    dots[row] = Dd;
  }
  __syncthreads();
  // phase 2: threads 0-63 pack f1 (kslot = t), 64-127 pack f2
  if (t < 128) {
    int g = t & 63;                        // kslot
    int is2 = t >> 6;
    const float* src = (is2 ? f2 : f1) + (size_t)row * D_DIM + g * 8;
    float sc = bc[is2];
    float4 v0 = *(const float4*)(src);
    float4 v1 = *(const float4*)(src + 4);
    int lo = __builtin_amdgcn_cvt_pk_fp8_f32(v0.x * sc, v0.y * sc, 0, false);
    lo     = __builtin_amdgcn_cvt_pk_fp8_f32(v0.z * sc, v0.w * sc, lo, true);
    int hi = __builtin_amdgcn_cvt_pk_fp8_f32(v1.x * sc, v1.y * sc, 0, false);
    hi     = __builtin_amdgcn_cvt_pk_fp8_f32(v1.z * sc, v1.w * sc, hi, true);
    int grow = row + is2 * B_ROWS;
    int panel = grow >> 8, rin = grow & 255;
    int2 pack; pack.x = lo; pack.y = hi;
    *(int2*)(fnb8 + (size_t)panel * PANEL_BYTES + g * 2048 + rin * 8) = pack;
  }
}

// ---- kernel 2: fp8 32x32 swapped-operand MFMA sim + in-register exp-sum/top-5 ----
// 512 thr (8 waves, 2x4 grid, wave tile 64x64), 48 KiB LDS -> 2 blocks/CU:
// independent blocks de-synchronize phases so MFMA/VALU/LDS/staging overlap.
__global__ __launch_bounds__(512, 4) void sim_kernel(
    const unsigned char* __restrict__ fnb8,
    float* __restrict__ partials)      // [N_ROWS][CSPLIT][6] = sum, top5 (desc)
{
  __shared__ int4 lds4[3072];          // 48 KiB = 2 double-buffers of (A+B)
  char* lds = (char*)lds4;

  // XCD-bijective mapping: XCD (bx&7) owns rowtiles 8x..8x+7 across all chunks
  int bx = blockIdx.x;                 // 0..511
  int xcd = bx & 7, kk = bx >> 3;      // kk: 0..63
  int rt = xcd * 8 + (kk & 7);         // 0..63
  int chunk = kk >> 3;                 // 0..7
  int rowbase = rt * BM;
  int chunkbase = chunk * COLS_PER_CHUNK;
  int panelA = rt >> 1, rhalf = rt & 1;

  int t = threadIdx.x;
  int wave = t >> 6, lane = t & 63;
  int wr = wave >> 2, wc = wave & 3;   // 2x4 wave grid; wave tile 64x64
  int l31 = lane & 31, lh = lane >> 5;

  float sum[2];
  float top[2][5];
  floatx16 acc[2][2];
  #pragma unroll
  for (int rb = 0; rb < 2; ++rb) {
    sum[rb] = 0.f;
    #pragma unroll
    for (int k = 0; k < 5; ++k) top[rb][k] = 0.f;
    #pragma unroll
    for (int cb = 0; cb < 2; ++cb)
      #pragma unroll
      for (int e = 0; e < 16; ++e) acc[rb][cb][e] = 0.0f;
  }

  const char* gA  = (const char*)fnb8 + (size_t)panelA * PANEL_BYTES + rhalf * 1024;
  const char* gB0 = (const char*)fnb8 + (size_t)(chunk * 4) * PANEL_BYTES;

  stage_tile(gA, gB0, lds, wave, lane);
  __syncthreads();                     // drains vmcnt -> tile 0 resident

  for (int it = 0; it < NIT; ++it) {
    int strip = it >> 3, kstep = it & 7, cur = it & 1;

    if (it + 1 < NIT) {
      int ns = (it + 1) >> 3, nk = (it + 1) & 7;
      stage_tile(gA + nk * KSTEP_BYTES,
                 gB0 + (size_t)ns * PANEL_BYTES + nk * KSTEP_BYTES,
                 lds + (cur ^ 1) * BUF_BYTES, wave, lane);
    }

    const char* As = lds + cur * BUF_BYTES;
    const char* Bs = As + TILE_A;
    #pragma unroll
    for (int ks = 0; ks < 4; ++ks) {
      int kslot = ks * 2 + lh;
      long rf0 = ldsFragA(As, wr * 64 + l31,      kslot);
      long rf1 = ldsFragA(As, wr * 64 + 32 + l31, kslot);
      long cf0 = ldsFragB(Bs, wc * 64 + l31,      kslot);
      long cf1 = ldsFragB(Bs, wc * 64 + 32 + l31, kslot);
      acc[0][0] = __builtin_amdgcn_mfma_f32_32x32x16_fp8_fp8(cf0, rf0, acc[0][0], 0, 0, 0);
      acc[0][1] = __builtin_amdgcn_mfma_f32_32x32x16_fp8_fp8(cf1, rf0, acc[0][1], 0, 0, 0);
      acc[1][0] = __builtin_amdgcn_mfma_f32_32x32x16_fp8_fp8(cf0, rf1, acc[1][0], 0, 0, 0);
      acc[1][1] = __builtin_amdgcn_mfma_f32_32x32x16_fp8_fp8(cf1, rf1, acc[1][1], 0, 0, 0);
    }

    if (kstep == 7) {                  // strip complete: poison diag, scan, reset
      // diagonal sub-block: this wave's rows == this strip's cols (wave-uniform)
      bool dwave = (rowbase + wr * 64) == (chunkbase + strip * BN + wc * 64);
      if (dwave && (((l31 >> 2) & 1) == lh)) {
        int rd = (l31 & 3) | (((l31 >> 3) & 3) << 2);
        acc[0][0][rd] = -1e30f;        // exp2 -> 0 (exact diag exclusion)
        acc[1][1][rd] = -1e30f;
      }
      scan_acc(acc, sum, top);
      #pragma unroll
      for (int rb = 0; rb < 2; ++rb)
        #pragma unroll
        for (int cb = 0; cb < 2; ++cb)
          #pragma unroll
          for (int e = 0; e < 16; ++e) acc[rb][cb][e] = 0.0f;
    }

    __syncthreads();                   // reads of cur done + next tile resident
  }

  // merge lane l <-> l+32 (same sim-rows, disjoint col subsets)
  #pragma unroll
  for (int rb = 0; rb < 2; ++rb) {
    sum[rb] += __shfl_xor(sum[rb], 32);
    float pt[5];
    #pragma unroll
    for (int k = 0; k < 5; ++k) pt[k] = __shfl_xor(top[rb][k], 32);
    #pragma unroll
    for (int k = 0; k < 5; ++k) insert5(top[rb], pt[k]);
  }

  // cross-wave merge: 4 wc-waves hold disjoint col ranges of the same rows
  float* mbuf = (float*)lds;           // [8 waves][2 rb][32 lanes][6] = 12 KiB
  if (lane < 32) {
    #pragma unroll
    for (int rb = 0; rb < 2; ++rb) {
      float* dst = mbuf + (size_t)(((wave * 2 + rb) * 32) + lane) * 6;
      dst[0] = sum[rb];
      #pragma unroll
      for (int k = 0; k < 5; ++k) dst[1 + k] = top[rb][k];
    }
  }
  __syncthreads();
  if (t < 128) {                       // thread t owns block-row t
    int wr2 = t >> 6, rb2 = (t >> 5) & 1, r31 = t & 31;
    float s = 0.0f;
    float a5[5] = {0.f, 0.f, 0.f, 0.f, 0.f};
    #pragma unroll
    for (int wc2 = 0; wc2 < 4; ++wc2) {
      int w = wr2 * 4 + wc2;
      const float* src = mbuf + (size_t)(((w * 2 + rb2) * 32) + r31) * 6;
      s += src[0];
      #pragma unroll
      for (int k = 0; k < 5; ++k) insert5(a5, src[1 + k]);
    }
    int grow = rowbase + t;
    float* dst = partials + ((size_t)grow * CSPLIT + chunk) * 6;
    dst[0] = s;
    #pragma unroll
    for (int k = 0; k < 5; ++k) dst[1 + k] = a5[k];
  }
}

// -------------------- kernel 3a: per-row loss, 32-block partial sums ----------
__global__ __launch_bounds__(256) void finalize1_kernel(
    const float* __restrict__ partials, const float* __restrict__ dots,
    float* __restrict__ bpart)
{
  int row = blockIdx.x * 256 + threadIdx.x;    // 32*256 = 8192
  const float* p = partials + (size_t)row * (CSPLIT * 6);
  float s = 0.0f;
  float a5[5] = {0.f, 0.f, 0.f, 0.f, 0.f};
  #pragma unroll
  for (int c = 0; c < CSPLIT; ++c) {
    s += p[c * 6];
    #pragma unroll
    for (int k = 0; k < 5; ++k) insert5(a5, p[c * 6 + 1 + k]);
  }
  float ng = s - (a5[0] + a5[1] + a5[2] + a5[3] + a5[4]);
  float dv = dots[row & (B_ROWS - 1)];
  float acc = __logf(ng + __expf(dv * INV_T)) - dv * INV_T;

  #pragma unroll
  for (int off = 32; off >= 1; off >>= 1) acc += __shfl_down(acc, off);
  __shared__ float red[4];
  int wave = threadIdx.x >> 6, lane = threadIdx.x & 63;
  if (lane == 0) red[wave] = acc;
  __syncthreads();
  if (threadIdx.x == 0)
    bpart[blockIdx.x] = red[0] + red[1] + red[2] + red[3];
}

// -------------------- kernel 3b: final reduce --------------------
__global__ __launch_bounds__(64) void finalize2_kernel(
    const float* __restrict__ bpart, float* __restrict__ out)
{
  int t = threadIdx.x;
  float v = (t < 32) ? bpart[t] : 0.0f;
  #pragma unroll
  for (int off = 32; off >= 1; off >>= 1) v += __shfl_down(v, off);
  if (t == 0) out[0] = v / (float)N_ROWS;
}

extern "C" void kernel_launch(void* const* d_in, const int* in_sizes, int n_in,
                              void* d_out, int out_size, void* d_ws, size_t ws_size,
                              hipStream_t stream) {
  const float* f1 = (const float*)d_in[0];
  const float* f2 = (const float*)d_in[1];
  float* out = (float*)d_out;
  char* ws = (char*)d_ws;

  unsigned char* fnb8 = (unsigned char*)ws;                           // 4 MiB
  float* dots = (float*)(ws + (size_t)4 * 1024 * 1024);               // 16 KiB
  float* partials = (float*)(ws + (size_t)4 * 1024 * 1024 + 65536);   // 1.5 MiB
  float* bpart = (float*)(ws + (size_t)8 * 1024 * 1024);              // 128 B

  prep_kernel<<<B_ROWS, 256, 0, stream>>>(f1, f2, fnb8, dots);
  sim_kernel<<<(N_ROWS / BM) * CSPLIT, 512, 0, stream>>>(fnb8, partials);
  finalize1_kernel<<<32, 256, 0, stream>>>(partials, dots, bpart);
  finalize2_kernel<<<1, 64, 0, stream>>>(bpart, out);
}

// Round 11
// 67.219 us; speedup vs baseline: 1.2862x; 1.2840x over previous
//
#include <hip/hip_runtime.h>
#include <hip/hip_bf16.h>

#define B_ROWS 4096
#define D_DIM  512
#define N_ROWS 8192
#define INV_T  20.0f
#define L2E_T  28.853900817779268f             // 20 / ln(2): exp(20x) = exp2(x*L2E_T)
#define EPS_N  1e-8f
#define CSPLIT 8
#define BM 256                                  // rows per block
#define BN 256                                  // cols per strip
#define COLS_PER_CHUNK (N_ROWS / CSPLIT)        // 1024
#define STRIPS (COLS_PER_CHUNK / BN)            // 4
#define NIT (STRIPS * 4)                        // 16 iterations, K=128 each
#define HALF_BYTES 32768                        // A or B: 4 kgroups x 256 rows x 32B
#define BUF_BYTES  65536                        // A + B per buffer
#define PANEL_BYTES 131072                      // [16 kgroup][256 row][32B] per panel
#define KITER_BYTES 32768                       // K=128 = 4 kgroups x 8KB

typedef __attribute__((ext_vector_type(16))) float floatx16;
typedef __attribute__((ext_vector_type(8)))  int   intx8;

#define AS1C(p) ((const __attribute__((address_space(1))) void*)(p))
#define AS3(p)  ((__attribute__((address_space(3))) void*)(p))

// MX scale 1.0 in E8M0 (bias 127), replicated in all bytes; opsel=0 picks byte 0
#define SC1 0x7F7F7F7F
#define MXMFMA(A, B, C) \
  __builtin_amdgcn_mfma_scale_f32_32x32x64_f8f6f4((A), (B), (C), 0, 0, 0, SC1, 0, SC1)

// k-group-major LDS tile: [4 kgroup][256 row][32B]; one frag = 32B contiguous,
// lanes 0-31 cover 1KB contiguous -> conflict-free (R9-verified pattern)
__device__ __forceinline__ intx8 ldsFrag32(const char* base, int row, int kgroup) {
  return *(const intx8*)(base + kgroup * 8192 + row * 32);
}

// sorted-insert via med3: new_t[i] = median(v, t[i], t[i-1]); all-ILP
__device__ __forceinline__ void insert5(float (&t)[5], float v) {
  float n0 = fmaxf(t[0], v);
  float n1 = __builtin_amdgcn_fmed3f(v, t[1], t[0]);
  float n2 = __builtin_amdgcn_fmed3f(v, t[2], t[1]);
  float n3 = __builtin_amdgcn_fmed3f(v, t[3], t[2]);
  float n4 = __builtin_amdgcn_fmed3f(v, t[4], t[3]);
  t[0] = n0; t[1] = n1; t[2] = n2; t[3] = n3; t[4] = n4;
}

// scan one strip: exp-sum + top-5 (diag already poisoned to -inf)
__device__ __forceinline__ void scan_acc(floatx16 (&acc)[2][2], float (&sum)[2],
                                         float (&top)[2][5]) {
  #pragma unroll
  for (int rb = 0; rb < 2; ++rb)
    #pragma unroll
    for (int cb = 0; cb < 2; ++cb)
      #pragma unroll
      for (int r = 0; r < 16; ++r) {
        float ev = exp2f(acc[rb][cb][r] * L2E_T);
        sum[rb] += ev;
        insert5(top[rb], ev);
      }
}

// stage one K=128 step: A half (32KB) + B half (32KB), both contiguous identity
// copies. 16 waves x 4KB each (4 x 16B-wide global_load_lds).
__device__ __forceinline__ void stage_tile(const char* gA_t, const char* gB_t,
                                           char* buf, int wave, int lane) {
  const char* src = ((wave < 8) ? gA_t : gB_t) + (wave & 7) * 4096 + lane * 16;
  char* dst = buf + ((wave < 8) ? 0 : HALF_BYTES) + (wave & 7) * 4096;
  #pragma unroll
  for (int q = 0; q < 4; ++q)
    __builtin_amdgcn_global_load_lds(AS1C(src + q * 1024), AS3(dst + q * 1024), 16, 0, 0);
}

// ---- kernel 1: normalize -> fp8 e4m3 in panel/kgroup32 layout, dot(f1,f2) ----
__global__ __launch_bounds__(256) void prep_kernel(
    const float* __restrict__ f1, const float* __restrict__ f2,
    unsigned char* __restrict__ fnb8, float* __restrict__ dots)
{
  int row = blockIdx.x;          // 0..4095
  int t = threadIdx.x;           // 256 threads, 2 elems each for the reduction
  const float* r1 = f1 + (size_t)row * D_DIM;
  const float* r2 = f2 + (size_t)row * D_DIM;
  float2 a = *(const float2*)(r1 + 2 * t);
  float2 b = *(const float2*)(r2 + 2 * t);
  float s1 = a.x * a.x + a.y * a.y;
  float s2 = b.x * b.x + b.y * b.y;
  float d  = a.x * b.x + a.y * b.y;
  #pragma unroll
  for (int off = 32; off >= 1; off >>= 1) {
    s1 += __shfl_down(s1, off);
    s2 += __shfl_down(s2, off);
    d  += __shfl_down(d, off);
  }
  __shared__ float red[4][3];
  __shared__ float bc[2];
  int wave = t >> 6, lane = t & 63;
  if (lane == 0) { red[wave][0] = s1; red[wave][1] = s2; red[wave][2] = d; }
  __syncthreads();
  if (t == 0) {
    float S1 = red[0][0] + red[1][0] + red[2][0] + red[3][0];
    float S2 = red[0][1] + red[1][1] + red[2][1] + red[3][1];
    float Dd = red[0][2] + red[1][2] + red[2][2] + red[3][2];
    bc[0] = 1.0f / fmaxf(sqrtf(S1), EPS_N);
    bc[1] = 1.0f / fmaxf(sqrtf(S2), EPS_N);
    dots[row] = Dd;
  }
  __syncthreads();
  // phase 2: threads 0-63 pack f1, 64-127 pack f2; thread handles 8 fp8 bytes
  if (t < 128) {
    int q = t & 63;
    int is2 = t >> 6;
    const float* src = (is2 ? f2 : f1) + (size_t)row * D_DIM + q * 8;
    float sc = bc[is2];
    float4 v0 = *(const float4*)(src);
    float4 v1 = *(const float4*)(src + 4);
    int lo = __builtin_amdgcn_cvt_pk_fp8_f32(v0.x * sc, v0.y * sc, 0, false);
    lo     = __builtin_amdgcn_cvt_pk_fp8_f32(v0.z * sc, v0.w * sc, lo, true);
    int hi = __builtin_amdgcn_cvt_pk_fp8_f32(v1.x * sc, v1.y * sc, 0, false);
    hi     = __builtin_amdgcn_cvt_pk_fp8_f32(v1.z * sc, v1.w * sc, hi, true);
    int grow = row + is2 * B_ROWS;
    int panel = grow >> 8, rin = grow & 255;
    int kgroup = q >> 2, inner = (q & 3) * 8;
    int2 pack; pack.x = lo; pack.y = hi;
    *(int2*)(fnb8 + (size_t)panel * PANEL_BYTES + kgroup * 8192 + rin * 32 + inner) = pack;
  }
}

// ---- kernel 2: MX fp8 32x32x64 swapped-operand MFMA + in-register exp-sum/top-5 ----
// 1024 thr, 4x4 wave grid, wave tile 64x64; K=128 per buffer (16 barriers)
__global__ __launch_bounds__(1024, 4) void sim_kernel(
    const unsigned char* __restrict__ fnb8,
    float* __restrict__ partials)      // [N_ROWS][CSPLIT][6] = sum, top5 (desc)
{
  __shared__ int4 lds4[8192];          // 128 KiB = 2 buffers of (A 32KB + B 32KB)
  char* lds = (char*)lds4;

  // XCD-bijective mapping: XCD (bx&7) owns rowtiles 4x..4x+3 across all chunks
  int bx = blockIdx.x;                 // 0..255
  int xcd = bx & 7, kk = bx >> 3;      // kk: 0..31
  int rt = xcd * 4 + (kk & 3);         // 0..31  (= A panel index)
  int chunk = kk >> 2;                 // 0..7
  int rowbase = rt * BM;
  int chunkbase = chunk * COLS_PER_CHUNK;

  int t = threadIdx.x;
  int wave = t >> 6, lane = t & 63;
  int wr = wave >> 2, wc = wave & 3;   // 4x4 wave grid; wave tile 64x64
  int l31 = lane & 31, lh = lane >> 5;

  float sum[2];
  float top[2][5];
  floatx16 acc[2][2];
  #pragma unroll
  for (int rb = 0; rb < 2; ++rb) {
    sum[rb] = 0.f;
    #pragma unroll
    for (int k = 0; k < 5; ++k) top[rb][k] = 0.f;
    #pragma unroll
    for (int cb = 0; cb < 2; ++cb)
      #pragma unroll
      for (int e = 0; e < 16; ++e) acc[rb][cb][e] = 0.0f;
  }

  const char* gA  = (const char*)fnb8 + (size_t)rt * PANEL_BYTES;
  const char* gB0 = (const char*)fnb8 + (size_t)(chunk * 4) * PANEL_BYTES;

  stage_tile(gA, gB0, lds, wave, lane);
  __syncthreads();                     // drains vmcnt -> tile 0 resident

  for (int it = 0; it < NIT; ++it) {
    int strip = it >> 2, kstep = it & 3, cur = it & 1;

    if (it + 1 < NIT) {
      int ns = (it + 1) >> 2, nk = (it + 1) & 3;
      stage_tile(gA + nk * KITER_BYTES,
                 gB0 + (size_t)ns * PANEL_BYTES + nk * KITER_BYTES,
                 lds + (cur ^ 1) * BUF_BYTES, wave, lane);
    }

    const char* As = lds + cur * BUF_BYTES;
    const char* Bs = As + HALF_BYTES;
    __builtin_amdgcn_s_setprio(1);
    #pragma unroll
    for (int m = 0; m < 2; ++m) {
      int kg = m * 2 + lh;             // kgroup 0..3 within buffer
      intx8 rf0 = ldsFrag32(As, wr * 64 + l31,      kg);
      intx8 rf1 = ldsFrag32(As, wr * 64 + 32 + l31, kg);
      intx8 cf0 = ldsFrag32(Bs, wc * 64 + l31,      kg);
      intx8 cf1 = ldsFrag32(Bs, wc * 64 + 32 + l31, kg);
      acc[0][0] = MXMFMA(cf0, rf0, acc[0][0]);
      acc[0][1] = MXMFMA(cf1, rf0, acc[0][1]);
      acc[1][0] = MXMFMA(cf0, rf1, acc[1][0]);
      acc[1][1] = MXMFMA(cf1, rf1, acc[1][1]);
    }
    __builtin_amdgcn_s_setprio(0);

    if (kstep == 3) {                  // strip complete: poison diag, scan, reset
      // diagonal sub-block: this wave's rows == this strip's cols (wave-uniform)
      bool dwave = (rowbase + wr * 64) == (chunkbase + strip * BN + wc * 64);
      if (dwave && (((l31 >> 2) & 1) == lh)) {
        int rd = (l31 & 3) | (((l31 >> 3) & 3) << 2);
        acc[0][0][rd] = -1e30f;        // exp2 -> 0 (exact diag exclusion)
        acc[1][1][rd] = -1e30f;
      }
      scan_acc(acc, sum, top);
      #pragma unroll
      for (int rb = 0; rb < 2; ++rb)
        #pragma unroll
        for (int cb = 0; cb < 2; ++cb)
          #pragma unroll
          for (int e = 0; e < 16; ++e) acc[rb][cb][e] = 0.0f;
    }

    __syncthreads();                   // reads of cur done + next tile resident
  }

  // merge lane l <-> l+32 (same sim-rows, disjoint col subsets)
  #pragma unroll
  for (int rb = 0; rb < 2; ++rb) {
    sum[rb] += __shfl_xor(sum[rb], 32);
    float pt[5];
    #pragma unroll
    for (int k = 0; k < 5; ++k) pt[k] = __shfl_xor(top[rb][k], 32);
    #pragma unroll
    for (int k = 0; k < 5; ++k) insert5(top[rb], pt[k]);
  }

  // cross-wave merge: 4 wc-waves hold disjoint col ranges of the same rows
  float* mbuf = (float*)lds;           // [16 waves][2 rb][32 lanes][6] = 24 KiB
  if (lane < 32) {
    #pragma unroll
    for (int rb = 0; rb < 2; ++rb) {
      float* dst = mbuf + (size_t)(((wave * 2 + rb) * 32) + lane) * 6;
      dst[0] = sum[rb];
      #pragma unroll
      for (int k = 0; k < 5; ++k) dst[1 + k] = top[rb][k];
    }
  }
  __syncthreads();
  if (t < 256) {                       // thread t owns block-row t
    int wr2 = t >> 6, rb2 = (t >> 5) & 1, r31 = t & 31;
    float s = 0.0f;
    float a5[5] = {0.f, 0.f, 0.f, 0.f, 0.f};
    #pragma unroll
    for (int wc2 = 0; wc2 < 4; ++wc2) {
      int w = wr2 * 4 + wc2;
      const float* src = mbuf + (size_t)(((w * 2 + rb2) * 32) + r31) * 6;
      s += src[0];
      #pragma unroll
      for (int k = 0; k < 5; ++k) insert5(a5, src[1 + k]);
    }
    int grow = rowbase + t;
    float* dst = partials + ((size_t)grow * CSPLIT + chunk) * 6;
    dst[0] = s;
    #pragma unroll
    for (int k = 0; k < 5; ++k) dst[1 + k] = a5[k];
  }
}

// -------------------- kernel 3a: per-row loss, 32-block partial sums ----------
__global__ __launch_bounds__(256) void finalize1_kernel(
    const float* __restrict__ partials, const float* __restrict__ dots,
    float* __restrict__ bpart)
{
  int row = blockIdx.x * 256 + threadIdx.x;    // 32*256 = 8192
  const float* p = partials + (size_t)row * (CSPLIT * 6);
  float s = 0.0f;
  float a5[5] = {0.f, 0.f, 0.f, 0.f, 0.f};
  #pragma unroll
  for (int c = 0; c < CSPLIT; ++c) {
    s += p[c * 6];
    #pragma unroll
    for (int k = 0; k < 5; ++k) insert5(a5, p[c * 6 + 1 + k]);
  }
  float ng = s - (a5[0] + a5[1] + a5[2] + a5[3] + a5[4]);
  float dv = dots[row & (B_ROWS - 1)];
  float acc = __logf(ng + __expf(dv * INV_T)) - dv * INV_T;

  #pragma unroll
  for (int off = 32; off >= 1; off >>= 1) acc += __shfl_down(acc, off);
  __shared__ float red[4];
  int wave = threadIdx.x >> 6, lane = threadIdx.x & 63;
  if (lane == 0) red[wave] = acc;
  __syncthreads();
  if (threadIdx.x == 0)
    bpart[blockIdx.x] = red[0] + red[1] + red[2] + red[3];
}

// -------------------- kernel 3b: final reduce --------------------
__global__ __launch_bounds__(64) void finalize2_kernel(
    const float* __restrict__ bpart, float* __restrict__ out)
{
  int t = threadIdx.x;
  float v = (t < 32) ? bpart[t] : 0.0f;
  #pragma unroll
  for (int off = 32; off >= 1; off >>= 1) v += __shfl_down(v, off);
  if (t == 0) out[0] = v / (float)N_ROWS;
}

extern "C" void kernel_launch(void* const* d_in, const int* in_sizes, int n_in,
                              void* d_out, int out_size, void* d_ws, size_t ws_size,
                              hipStream_t stream) {
  const float* f1 = (const float*)d_in[0];
  const float* f2 = (const float*)d_in[1];
  float* out = (float*)d_out;
  char* ws = (char*)d_ws;

  unsigned char* fnb8 = (unsigned char*)ws;                           // 4 MiB
  float* dots = (float*)(ws + (size_t)4 * 1024 * 1024);               // 16 KiB
  float* partials = (float*)(ws + (size_t)4 * 1024 * 1024 + 65536);   // 1.5 MiB
  float* bpart = (float*)(ws + (size_t)8 * 1024 * 1024);              // 128 B

  prep_kernel<<<B_ROWS, 256, 0, stream>>>(f1, f2, fnb8, dots);
  sim_kernel<<<(N_ROWS / BM) * CSPLIT, 1024, 0, stream>>>(fnb8, partials);
  finalize1_kernel<<<32, 256, 0, stream>>>(partials, dots, bpart);
  finalize2_kernel<<<1, 64, 0, stream>>>(bpart, out);
}